// Round 9
// baseline (187.531 us; speedup 1.0000x reference)
//
#include <hip/hip_runtime.h>

#define N_NODES 30000
#define N_EDGES 480000
#define D 128
#define H 3
#define BN_EPS 1e-5f
#define M_TOT (H * N_NODES)
#define E_TOT (H * N_EDGES)

#define NCH 64                       // chunks per hop
#define CHE (N_EDGES / NCH)          // 7500 edges per chunk
#define NBKT 512                     // dst buckets per hop (dst>>6)
#define NBKT_TOT (H * NBKT)          // 1536
#define CELLS (NBKT_TOT * NCH)       // 98304 = 96 * 1024
#define SCAN_NBLK (CELLS / 1024)     // 96
#define CONV_N4 (3 * N_NODES * D / 4)        // slices 1..3 only
#define CONV_BLK ((CONV_N4 + 255) / 256)     // 11250

typedef __attribute__((ext_vector_type(8))) short short8v;   // 8 x bf16
typedef __attribute__((ext_vector_type(4))) float f32x4;     // MFMA accumulator

__device__ __forceinline__ ushort f2bf(float f) {            // RNE f32 -> bf16
    uint u = __float_as_uint(f);
    u += 0x7fffu + ((u >> 16) & 1u);
    return (ushort)(u >> 16);
}
__device__ __forceinline__ float bf2f(ushort b) {
    return __uint_as_float(((uint)b) << 16);
}

// ---------------- merged prep: weights^T + BN coeffs + bf16 conv (slices 1-3)
__global__ __launch_bounds__(256) void prep_k(
    const float* __restrict__ xs,
    const float* __restrict__ lW1, const float* __restrict__ lW2,
    const float* __restrict__ cW1, const float* __restrict__ cW2,
    const float* __restrict__ lb1, const float* __restrict__ lg,
    const float* __restrict__ lbt, const float* __restrict__ lm,
    const float* __restrict__ lv,
    const float* __restrict__ cb1, const float* __restrict__ cg,
    const float* __restrict__ cbt, const float* __restrict__ cm,
    const float* __restrict__ cv,
    const float* __restrict__ lb2, const float* __restrict__ cb2,
    ushort* __restrict__ Wt, float* __restrict__ scof,
    ushort* __restrict__ xball)
{
    const int bid = blockIdx.x;
    const int tid = threadIdx.x;
    if (bid < 8) {                           // transpose+convert weight mat bid
        const float* src;
        if (bid == 0) src = lW1;
        else if (bid == 1) src = lW2;
        else {
            const int k = (bid - 2) >> 1;
            src = ((bid & 1) == 0 ? cW1 : cW2) + (size_t)k * D * D;
        }
        ushort* dst = Wt + (size_t)bid * D * D;
        for (int idx = tid; idx < D * D; idx += 256) {
            const int n = idx >> 7, k = idx & 127;
            dst[idx] = f2bf(src[k * D + n]);
        }
    } else if (bid == 8) {                   // BN scale/offset + total bias
        for (int t = tid; t < 512; t += 256) {
            const int L = t >> 7, c = t & 127;
            float g, v, b, m, bt;
            if (L == 0) { g = lg[c]; v = lv[c]; b = lb1[c]; m = lm[c]; bt = lbt[c]; }
            else {
                const int k = L - 1;
                g = cg[k * D + c]; v = cv[k * D + c]; b = cb1[k * D + c];
                m = cm[k * D + c]; bt = cbt[k * D + c];
            }
            const float s = g * rsqrtf(v + BN_EPS);
            scof[L * 256 + c] = s;
            scof[L * 256 + 128 + c] = (b - m) * s + bt;
        }
        if (tid < 128) {                     // btot = lb2 + sum_k cb2[k]
            float t = lb2[tid];
            for (int k = 0; k < H; ++k) t += cb2[k * D + tid];
            scof[1024 + tid] = t;
        }
    } else {                                 // f32 -> bf16 for xs slices 1..3
        const int i = (bid - 9) * 256 + tid;
        if (i < CONV_N4) {
            const float4 v = ((const float4*)(xs + (size_t)N_NODES * D))[i];
            ushort4 o;
            o.x = f2bf(v.x); o.y = f2bf(v.y); o.z = f2bf(v.z); o.w = f2bf(v.w);
            ((ushort4*)(xball + (size_t)N_NODES * D))[i] = o;
        }
    }
}

// ---------------- Fused 4-layer MLP, layer-parallel, 128-VGPR budget -------
// Block = 16 rows x 4 waves (wave L = layer L). __launch_bounds__(256,4)
// matches the LDS-limited 4 waves/SIMD and doubles the VGPR budget so the
// 8 B-fragments per k-step stay in flight (round-8 had VGPR=60 -> serialized
// L2 round-trips; that was the ~70us latency floor).
#define LWH 136   // h row stride (ushorts)
#define PSW 132   // partial row stride (f32)

__global__ __launch_bounds__(256, 4) void fused4_k(
    const float* __restrict__ xs0, const ushort* __restrict__ zb,
    const ushort* __restrict__ Wt, const float* __restrict__ scof,
    float* __restrict__ out)
{
    __shared__ float Ps[4 * 16 * PSW];       // 33.8 KB; wave L owns Ps[L*16*PSW..]
    const int tid = threadIdx.x;
    const int L = tid >> 6, lane = tid & 63;
    const int m16 = lane & 15, kq = lane >> 4;
    const int row0 = blockIdx.x * 16;        // 30000 = 1875*16, always in range

    const ushort* W1t = Wt + (size_t)(2 * L) * D * D;
    const ushort* W2t = W1t + D * D;
    const float* scL = scof + L * 256;

    // A fragments: row = m16, k = kk*32 + kq*8 + j
    short8v a[4];
    if (L == 0) {
        const float* xp = xs0 + (size_t)(row0 + m16) * D + kq * 8;
#pragma unroll
        for (int kk = 0; kk < 4; ++kk) {
            const float4 f0 = *(const float4*)(xp + kk * 32);
            const float4 f1 = *(const float4*)(xp + kk * 32 + 4);
            short8v av;
            av[0] = (short)f2bf(f0.x); av[1] = (short)f2bf(f0.y);
            av[2] = (short)f2bf(f0.z); av[3] = (short)f2bf(f0.w);
            av[4] = (short)f2bf(f1.x); av[5] = (short)f2bf(f1.y);
            av[6] = (short)f2bf(f1.z); av[7] = (short)f2bf(f1.w);
            a[kk] = av;
        }
    } else {
        const ushort* xp = zb + (size_t)(L - 1) * N_NODES * D
                              + (size_t)(row0 + m16) * D + kq * 8;
#pragma unroll
        for (int kk = 0; kk < 4; ++kk)
            a[kk] = *(const short8v*)(xp + kk * 32);
    }

    // GEMM1: per k-step, batch all 8 B-frag loads before the 8 MFMAs
    f32x4 acc[8];
#pragma unroll
    for (int t = 0; t < 8; ++t) acc[t] = (f32x4){0.f, 0.f, 0.f, 0.f};
#pragma unroll
    for (int kk = 0; kk < 4; ++kk) {
        short8v bfr[8];
#pragma unroll
        for (int t = 0; t < 8; ++t)
            bfr[t] = *(const short8v*)(W1t + (t * 16 + m16) * D + kk * 32 + kq * 8);
#pragma unroll
        for (int t = 0; t < 8; ++t)
            acc[t] = __builtin_amdgcn_mfma_f32_16x16x32_bf16(a[kk], bfr[t], acc[t], 0, 0, 0);
    }

    // epilogue 1: h = relu(bn(.)) -> wave-private LDS (reuses partial region)
    ushort* Hs = (ushort*)&Ps[L * 16 * PSW];
#pragma unroll
    for (int t = 0; t < 8; ++t) {
        const int n = t * 16 + m16;
        const float sc = scL[n], of = scL[128 + n];
#pragma unroll
        for (int r = 0; r < 4; ++r)
            Hs[(kq * 4 + r) * LWH + n] = f2bf(fmaxf(acc[t][r] * sc + of, 0.f));
    }
    short8v ah[4];
#pragma unroll
    for (int kk = 0; kk < 4; ++kk)
        ah[kk] = *(const short8v*)(&Hs[m16 * LWH + kk * 32 + kq * 8]);

    // GEMM2, same batched-B structure
    f32x4 accO[8];
#pragma unroll
    for (int t = 0; t < 8; ++t) accO[t] = (f32x4){0.f, 0.f, 0.f, 0.f};
#pragma unroll
    for (int kk = 0; kk < 4; ++kk) {
        short8v bfr[8];
#pragma unroll
        for (int t = 0; t < 8; ++t)
            bfr[t] = *(const short8v*)(W2t + (t * 16 + m16) * D + kk * 32 + kq * 8);
#pragma unroll
        for (int t = 0; t < 8; ++t)
            accO[t] = __builtin_amdgcn_mfma_f32_16x16x32_bf16(ah[kk], bfr[t], accO[t], 0, 0, 0);
    }

    // write f32 partial (D-frag: row = kq*4+r, col = t*16+m16)
#pragma unroll
    for (int t = 0; t < 8; ++t) {
        const int n = t * 16 + m16;
#pragma unroll
        for (int r = 0; r < 4; ++r)
            Ps[L * 16 * PSW + (kq * 4 + r) * PSW + n] = accO[t][r];
    }
    __syncthreads();

    // reduce 4 partials + total bias, vectorized f32x4, coalesced store
    const float4* btot4 = (const float4*)(scof + 1024);
    for (int idx = tid; idx < 512; idx += 256) {
        const int r = idx >> 5, c = idx & 31;
        const int base = r * PSW + c * 4;
        float4 s0 = *(const float4*)(&Ps[base]);
        const float4 s1 = *(const float4*)(&Ps[16 * PSW + base]);
        const float4 s2 = *(const float4*)(&Ps[32 * PSW + base]);
        const float4 s3 = *(const float4*)(&Ps[48 * PSW + base]);
        const float4 bb = btot4[c];
        s0.x = (s0.x + s1.x) + (s2.x + s3.x) + bb.x;
        s0.y = (s0.y + s1.y) + (s2.y + s3.y) + bb.y;
        s0.z = (s0.z + s1.z) + (s2.z + s3.z) + bb.z;
        s0.w = (s0.w + s1.w) + (s2.w + s3.w) + bb.w;
        *(float4*)(out + (size_t)(row0 + r) * D + c * 4) = s0;
    }
}

// ---------------- CSR build: deterministic two-pass multisplit -------------
__global__ __launch_bounds__(256) void bincount_k(const int* __restrict__ ei,
                                                  int* __restrict__ cnts) {
    __shared__ int hc[NBKT];
    const int chunk = blockIdx.x;
    const int hop = chunk >> 6, c = chunk & 63;
    for (int i = threadIdx.x; i < NBKT; i += 256) hc[i] = 0;
    __syncthreads();
    const int* dstp = ei + (size_t)hop * 2 * N_EDGES + N_EDGES + c * CHE;
    for (int i = threadIdx.x; i < CHE; i += 256)
        atomicAdd(&hc[dstp[i] >> 6], 1);
    __syncthreads();
    for (int b = threadIdx.x; b < NBKT; b += 256)
        cnts[((hop * NBKT + b) << 6) | c] = hc[b];
}

__global__ __launch_bounds__(1024) void scanA_k(int* __restrict__ cnts,
                                                int* __restrict__ bsums) {
    __shared__ int sh[1024];
    const int tid = threadIdx.x;
    const int i = blockIdx.x * 1024 + tid;
    const int v = cnts[i];
    sh[tid] = v;
    __syncthreads();
    int val = v;
    for (int off = 1; off < 1024; off <<= 1) {
        const int t = (tid >= off) ? sh[tid - off] : 0;
        __syncthreads();
        val += t;
        sh[tid] = val;
        __syncthreads();
    }
    cnts[i] = val - v;
    if (tid == 1023) bsums[blockIdx.x] = val;
}

// scanC with fused block-sum scan (each block redundantly scans 96 sums in LDS)
__global__ __launch_bounds__(1024) void scanC_k(int* __restrict__ cnts,
                                                const int* __restrict__ bsums,
                                                int* __restrict__ offs) {
    __shared__ int bs[128];
    const int tid = threadIdx.x;
    if (tid < 128) bs[tid] = (tid < SCAN_NBLK) ? bsums[tid] : 0;
    __syncthreads();
    for (int off = 1; off < 128; off <<= 1) {
        int t = 0;
        if (tid < 128 && tid >= off) t = bs[tid - off];
        __syncthreads();
        if (tid < 128) bs[tid] += t;
        __syncthreads();
    }
    const int add = (blockIdx.x == 0) ? 0 : bs[blockIdx.x - 1];
    const int i = blockIdx.x * 1024 + tid;
    cnts[i] += add;
    if (i == 0) offs[M_TOT] = E_TOT;
}

__global__ __launch_bounds__(256) void binplace_k(const int* __restrict__ ei,
                                                  const int* __restrict__ cnts,
                                                  uint* __restrict__ binned) {
    __shared__ int cur[NBKT];
    const int chunk = blockIdx.x;
    const int hop = chunk >> 6, c = chunk & 63;
    for (int b = threadIdx.x; b < NBKT; b += 256)
        cur[b] = cnts[((hop * NBKT + b) << 6) | c];
    __syncthreads();
    const int* srcp = ei + (size_t)hop * 2 * N_EDGES + c * CHE;
    const int* dstp = srcp + N_EDGES;
    for (int i = threadIdx.x; i < CHE; i += 256) {
        const int s = srcp[i], d = dstp[i];
        const int slot = atomicAdd(&cur[d >> 6], 1);
        binned[slot] = ((uint)(d & 63) << 16) | (uint)s;
    }
}

__global__ __launch_bounds__(256) void cat_k(const uint* __restrict__ binned,
                                             const int* __restrict__ cnts,
                                             int* __restrict__ offs,
                                             ushort* __restrict__ srcs) {
    const int B = blockIdx.x;
    const int hop = B >> 9, bb = B & 511;
    const int dstbase = bb << 6;
    if (dstbase >= N_NODES) return;
    const int bB = cnts[B << 6];
    const int bE = (B == NBKT_TOT - 1) ? E_TOT : cnts[(B + 1) << 6];
    const int cnt = bE - bB;

    __shared__ uint ent[2048];
    __shared__ ushort stg[2048];
    __shared__ int hist[64], cur[64];

    for (int d = threadIdx.x; d < 64; d += 256) hist[d] = 0;
    __syncthreads();
    for (int i = threadIdx.x; i < cnt; i += 256) {
        const uint e = binned[bB + i];
        ent[i] = e;
        atomicAdd(&hist[e >> 16], 1);
    }
    __syncthreads();
    if (threadIdx.x < 64) {
        const int v = hist[threadIdx.x];
        int x = v;
        for (int off = 1; off < 64; off <<= 1) {
            const int t = __shfl_up(x, off, 64);
            if (threadIdx.x >= off) x += t;
        }
        cur[threadIdx.x] = x - v;
        const int gd = dstbase + threadIdx.x;
        if (gd < N_NODES) offs[hop * N_NODES + gd] = bB + x - v;
    }
    __syncthreads();
    for (int i = threadIdx.x; i < cnt; i += 256) {
        const uint e = ent[i];
        const int lp = atomicAdd(&cur[e >> 16], 1);
        stg[lp] = (ushort)(e & 0xffffu);
    }
    __syncthreads();
    for (int i = threadIdx.x; i < cnt; i += 256)
        srcs[bB + i] = stg[i];
}

// ---------------- GIN aggregation, all 3 hops in one launch ----------------
// (round-6 version: 4 edge-streams of 16 lanes x uint4, 32 edges in flight)
__global__ __launch_bounds__(256) void agg_k(const ushort* __restrict__ xball,
                                             const int* __restrict__ offs,
                                             const ushort* __restrict__ srcs,
                                             const float* __restrict__ eps,
                                             ushort* __restrict__ zb) {
    const int gnode = blockIdx.x * 4 + (threadIdx.x >> 6);   // 0..89999
    const int hop = gnode / N_NODES;
    const int node = gnode - hop * N_NODES;
    const int lane = threadIdx.x & 63;
    const int eh = lane >> 4;            // edge stream 0..3
    const int cl = lane & 15;            // 16B chunk within the 256B row
    const float a = 1.0f + eps[hop];
    const uint4* x4 = (const uint4*)(xball + (size_t)(hop + 1) * N_NODES * D);

    float acc[8];
#pragma unroll
    for (int q = 0; q < 8; ++q) acc[q] = 0.f;
    if (eh == 0) {                       // self term on stream 0
        const uint4 sv = x4[(size_t)node * 16 + cl];
        const uint w[4] = {sv.x, sv.y, sv.z, sv.w};
#pragma unroll
        for (int q = 0; q < 4; ++q) {
            acc[2 * q]     = a * bf2f((ushort)(w[q] & 0xffff));
            acc[2 * q + 1] = a * bf2f((ushort)(w[q] >> 16));
        }
    }

    const int beg = offs[gnode], end = offs[gnode + 1];
    for (int i = beg; i < end; i += 32) {
        uint4 v[8];
#pragma unroll
        for (int u = 0; u < 8; ++u) {
            const int p = i + u * 4 + eh;
            v[u] = make_uint4(0u, 0u, 0u, 0u);
            if (p < end) v[u] = x4[(size_t)srcs[p] * 16 + cl];
        }
#pragma unroll
        for (int u = 0; u < 8; ++u) {
            const uint w[4] = {v[u].x, v[u].y, v[u].z, v[u].w};
#pragma unroll
            for (int q = 0; q < 4; ++q) {
                acc[2 * q]     += bf2f((ushort)(w[q] & 0xffff));
                acc[2 * q + 1] += bf2f((ushort)(w[q] >> 16));
            }
        }
    }
#pragma unroll
    for (int q = 0; q < 8; ++q) {
        acc[q] += __shfl_xor(acc[q], 16);
        acc[q] += __shfl_xor(acc[q], 32);
    }
    if (eh == 0) {
        uint4 o;
        o.x = (uint)f2bf(acc[0]) | ((uint)f2bf(acc[1]) << 16);
        o.y = (uint)f2bf(acc[2]) | ((uint)f2bf(acc[3]) << 16);
        o.z = (uint)f2bf(acc[4]) | ((uint)f2bf(acc[5]) << 16);
        o.w = (uint)f2bf(acc[6]) | ((uint)f2bf(acc[7]) << 16);
        ((uint4*)zb)[(size_t)gnode * 16 + cl] = o;
    }
}

// ---------------- driver ----------------
extern "C" void kernel_launch(void* const* d_in, const int* in_sizes, int n_in,
                              void* d_out, int out_size, void* d_ws, size_t ws_size,
                              hipStream_t stream)
{
    const float* xs  = (const float*)d_in[0];
    const int*   ei  = (const int*)d_in[1];
    const float* lW1 = (const float*)d_in[2];
    const float* lb1 = (const float*)d_in[3];
    const float* lg  = (const float*)d_in[4];
    const float* lbt = (const float*)d_in[5];
    const float* lm  = (const float*)d_in[6];
    const float* lv  = (const float*)d_in[7];
    const float* lW2 = (const float*)d_in[8];
    const float* lb2 = (const float*)d_in[9];
    const float* eps = (const float*)d_in[10];
    const float* cW1 = (const float*)d_in[11];
    const float* cb1 = (const float*)d_in[12];
    const float* cg  = (const float*)d_in[13];
    const float* cbt = (const float*)d_in[14];
    const float* cm  = (const float*)d_in[15];
    const float* cv  = (const float*)d_in[16];
    const float* cW2 = (const float*)d_in[17];
    const float* cb2 = (const float*)d_in[18];
    float* out = (float*)d_out;

    char* ws = (char*)d_ws;
    ushort* xball = (ushort*)ws; ws += (size_t)4 * N_NODES * D * sizeof(ushort);
    ushort* zb    = (ushort*)ws; ws += (size_t)H * N_NODES * D * sizeof(ushort);
    ushort* Wt    = (ushort*)ws; ws += (size_t)8 * D * D * sizeof(ushort);
    float*  scof  = (float*)ws;  ws += (size_t)(4 * 256 + 128) * sizeof(float);
    int* cnts     = (int*)ws;    ws += (size_t)CELLS * sizeof(int);
    int* bsums    = (int*)ws;    ws += 128 * sizeof(int);
    int* offs     = (int*)ws;    ws += (size_t)(M_TOT + 64) * sizeof(int);
    uint* binned  = (uint*)ws;   ws += (size_t)E_TOT * sizeof(uint);
    ushort* srcs  = (ushort*)ws;

    // merged prep: weights^T (blocks 0-7), BN coeffs (8), bf16 conv (9+)
    prep_k<<<9 + CONV_BLK, 256, 0, stream>>>(xs, lW1, lW2, cW1, cW2,
                                             lb1, lg, lbt, lm, lv,
                                             cb1, cg, cbt, cm, cv,
                                             lb2, cb2, Wt, scof, xball);

    // CSR via multisplit (scanB fused into scanC)
    bincount_k<<<H * NCH, 256, 0, stream>>>(ei, cnts);
    scanA_k<<<SCAN_NBLK, 1024, 0, stream>>>(cnts, bsums);
    scanC_k<<<SCAN_NBLK, 1024, 0, stream>>>(cnts, bsums, offs);
    binplace_k<<<H * NCH, 256, 0, stream>>>(ei, cnts, binned);
    cat_k<<<NBKT_TOT, 256, 0, stream>>>(binned, cnts, offs, srcs);

    // aggregation for all 3 hops, then the layer-parallel fused MLP
    agg_k<<<M_TOT / 4, 256, 0, stream>>>(xball, offs, srcs, eps, zb);
    fused4_k<<<N_NODES / 16, 256, 0, stream>>>(xs, zb, Wt, scof, out);
}

// Round 10
// 176.798 us; speedup vs baseline: 1.0607x; 1.0607x over previous
//
#include <hip/hip_runtime.h>

#define N_NODES 30000
#define N_EDGES 480000
#define D 128
#define H 3
#define BN_EPS 1e-5f
#define M_TOT (H * N_NODES)
#define E_TOT (H * N_EDGES)

#define NCH 64                       // chunks per hop
#define CHE (N_EDGES / NCH)          // 7500 edges per chunk
#define NBKT 512                     // dst buckets per hop (dst>>6)
#define NBKT_TOT (H * NBKT)          // 1536
#define CELLS (NBKT_TOT * NCH)       // 98304 = 96 * 1024
#define SCAN_NBLK (CELLS / 1024)     // 96
#define CONV_N4 (3 * N_NODES * D / 4)        // slices 1..3 only
#define CONV_BLK ((CONV_N4 + 255) / 256)     // 11250
#define TILES ((N_NODES + 63) / 64)          // 469

typedef __attribute__((ext_vector_type(8))) short short8v;   // 8 x bf16
typedef __attribute__((ext_vector_type(4))) float f32x4;     // MFMA accumulator

__device__ __forceinline__ ushort f2bf(float f) {            // RNE f32 -> bf16
    uint u = __float_as_uint(f);
    u += 0x7fffu + ((u >> 16) & 1u);
    return (ushort)(u >> 16);
}
__device__ __forceinline__ float bf2f(ushort b) {
    return __uint_as_float(((uint)b) << 16);
}

// ---------------- merged prep: weights^T + BN coeffs + bf16 conv (slices 1-3)
__global__ __launch_bounds__(256) void prep_k(
    const float* __restrict__ xs,
    const float* __restrict__ lW1, const float* __restrict__ lW2,
    const float* __restrict__ cW1, const float* __restrict__ cW2,
    const float* __restrict__ lb1, const float* __restrict__ lg,
    const float* __restrict__ lbt, const float* __restrict__ lm,
    const float* __restrict__ lv,
    const float* __restrict__ cb1, const float* __restrict__ cg,
    const float* __restrict__ cbt, const float* __restrict__ cm,
    const float* __restrict__ cv,
    const float* __restrict__ lb2, const float* __restrict__ cb2,
    ushort* __restrict__ Wt, float* __restrict__ scof,
    ushort* __restrict__ xball)
{
    const int bid = blockIdx.x;
    const int tid = threadIdx.x;
    if (bid < 8) {                           // transpose+convert weight mat bid
        const float* src;
        if (bid == 0) src = lW1;
        else if (bid == 1) src = lW2;
        else {
            const int k = (bid - 2) >> 1;
            src = ((bid & 1) == 0 ? cW1 : cW2) + (size_t)k * D * D;
        }
        ushort* dst = Wt + (size_t)bid * D * D;
        for (int idx = tid; idx < D * D; idx += 256) {
            const int n = idx >> 7, k = idx & 127;
            dst[idx] = f2bf(src[k * D + n]);
        }
    } else if (bid == 8) {                   // BN scale/offset + total bias
        for (int t = tid; t < 512; t += 256) {
            const int L = t >> 7, c = t & 127;
            float g, v, b, m, bt;
            if (L == 0) { g = lg[c]; v = lv[c]; b = lb1[c]; m = lm[c]; bt = lbt[c]; }
            else {
                const int k = L - 1;
                g = cg[k * D + c]; v = cv[k * D + c]; b = cb1[k * D + c];
                m = cm[k * D + c]; bt = cbt[k * D + c];
            }
            const float s = g * rsqrtf(v + BN_EPS);
            scof[L * 256 + c] = s;
            scof[L * 256 + 128 + c] = (b - m) * s + bt;
        }
        if (tid < 128) {                     // btot = lb2 + sum_k cb2[k]
            float t = lb2[tid];
            for (int k = 0; k < H; ++k) t += cb2[k * D + tid];
            scof[1024 + tid] = t;
        }
    } else {                                 // f32 -> bf16 for xs slices 1..3
        const int i = (bid - 9) * 256 + tid;
        if (i < CONV_N4) {
            const float4 v = ((const float4*)(xs + (size_t)N_NODES * D))[i];
            ushort4 o;
            o.x = f2bf(v.x); o.y = f2bf(v.y); o.z = f2bf(v.z); o.w = f2bf(v.w);
            ((ushort4*)(xball + (size_t)N_NODES * D))[i] = o;
        }
    }
}

// ---------------- Layer-parallel MLP: block = (tile, layer) ----------------
// Grid 469*4: L = bid&3, tile = bid>>2. 64-row tile, 4 waves (wave w = rows
// w*16..+16). X + W1 staged to LDS; GEMM1; h (wave-private rows of Xs) +
// W2 restage; GEMM2; bf16 partial write to parts[L]. 3 barriers. The 4
// layers run in CONCURRENT BLOCKS (vs R6's in-block serial loop).
#define LW 136

__global__ __launch_bounds__(256) void layerpar_k(
    const float* __restrict__ xs0, const ushort* __restrict__ zb,
    const ushort* __restrict__ Wt, const float* __restrict__ scof,
    ushort* __restrict__ parts)
{
    __shared__ ushort Xs[64 * LW];    // 17.4 KB (A tile, then h tile)
    __shared__ ushort Ws[128 * LW];   // 34.8 KB (W1, then W2)
    const int L = blockIdx.x & 3, tile = blockIdx.x >> 2;
    const int row0 = tile * 64;
    const int tid = threadIdx.x;
    const int wave = tid >> 6, lane = tid & 63;
    const int m16 = lane & 15, kq = lane >> 4;

    const ushort* W1t = Wt + (size_t)(2 * L) * D * D;
    const ushort* W2t = W1t + D * D;
    const float* scL = scof + L * 256;

    // stage X tile
    if (L == 0) {
        for (int f = tid; f < 2048; f += 256) {
            const int r = f >> 5, c4 = (f & 31) << 2;
            const int gr = row0 + r;
            ushort4 v = make_ushort4(0, 0, 0, 0);
            if (gr < N_NODES) {
                const float4 fv = *(const float4*)(xs0 + (size_t)gr * D + c4);
                v.x = f2bf(fv.x); v.y = f2bf(fv.y);
                v.z = f2bf(fv.z); v.w = f2bf(fv.w);
            }
            *(ushort4*)(&Xs[r * LW + c4]) = v;
        }
    } else {
        const ushort* X = zb + (size_t)(L - 1) * N_NODES * D;
        for (int f = tid; f < 2048; f += 256) {
            const int r = f >> 5, c4 = (f & 31) << 2;
            const int gr = row0 + r;
            ushort4 v = make_ushort4(0, 0, 0, 0);
            if (gr < N_NODES) v = *(const ushort4*)(X + (size_t)gr * D + c4);
            *(ushort4*)(&Xs[r * LW + c4]) = v;
        }
    }
    // stage W1
    for (int f = tid; f < 4096; f += 256) {
        const int n = f >> 5, c4 = (f & 31) << 2;
        *(ushort4*)(&Ws[n * LW + c4]) = *(const ushort4*)(W1t + n * D + c4);
    }
    __syncthreads();

    // A fragments to registers (frees Xs for the h tile)
    const int arow = wave * 16 + m16;
    short8v a[4];
#pragma unroll
    for (int kk = 0; kk < 4; ++kk)
        a[kk] = *(const short8v*)(&Xs[arow * LW + kk * 32 + kq * 8]);

    // GEMM1
    f32x4 acc[8];
#pragma unroll
    for (int t = 0; t < 8; ++t) acc[t] = (f32x4){0.f, 0.f, 0.f, 0.f};
#pragma unroll
    for (int kk = 0; kk < 4; ++kk) {
#pragma unroll
        for (int t = 0; t < 8; ++t) {
            const short8v b = *(const short8v*)(&Ws[(t * 16 + m16) * LW + kk * 32 + kq * 8]);
            acc[t] = __builtin_amdgcn_mfma_f32_16x16x32_bf16(a[kk], b, acc[t], 0, 0, 0);
        }
    }
    __syncthreads();   // Ws readers + Xs reg-reads done

    // epilogue 1: h = relu(bn(.)) into wave-private Xs rows; restage Ws = W2
#pragma unroll
    for (int t = 0; t < 8; ++t) {
        const int n = t * 16 + m16;
        const float sc = scL[n], of = scL[128 + n];
#pragma unroll
        for (int r = 0; r < 4; ++r)
            Xs[(wave * 16 + kq * 4 + r) * LW + n] = f2bf(fmaxf(acc[t][r] * sc + of, 0.f));
    }
    for (int f = tid; f < 4096; f += 256) {
        const int n = f >> 5, c4 = (f & 31) << 2;
        *(ushort4*)(&Ws[n * LW + c4]) = *(const ushort4*)(W2t + n * D + c4);
    }
    __syncthreads();

    // GEMM2
    short8v ah[4];
#pragma unroll
    for (int kk = 0; kk < 4; ++kk)
        ah[kk] = *(const short8v*)(&Xs[arow * LW + kk * 32 + kq * 8]);
    f32x4 accO[8];
#pragma unroll
    for (int t = 0; t < 8; ++t) accO[t] = (f32x4){0.f, 0.f, 0.f, 0.f};
#pragma unroll
    for (int kk = 0; kk < 4; ++kk) {
#pragma unroll
        for (int t = 0; t < 8; ++t) {
            const short8v b = *(const short8v*)(&Ws[(t * 16 + m16) * LW + kk * 32 + kq * 8]);
            accO[t] = __builtin_amdgcn_mfma_f32_16x16x32_bf16(ah[kk], b, accO[t], 0, 0, 0);
        }
    }

    // bf16 partial write: parts[L][row][col]
    ushort* pL = parts + (size_t)L * N_NODES * D;
#pragma unroll
    for (int t = 0; t < 8; ++t) {
        const int n = t * 16 + m16;
#pragma unroll
        for (int r = 0; r < 4; ++r) {
            const int gr = row0 + wave * 16 + kq * 4 + r;
            if (gr < N_NODES) pL[(size_t)gr * D + n] = f2bf(accO[t][r]);
        }
    }
}

// ---------------- reduce: out = sum_L parts[L] + btot (f32, fixed order) ---
__global__ __launch_bounds__(256) void reduce_k(const ushort* __restrict__ parts,
                                                const float* __restrict__ scof,
                                                float* __restrict__ out)
{
    const int i = blockIdx.x * 256 + threadIdx.x;    // uint2 granule = 4 cols
    const size_t LS = (size_t)N_NODES * D / 4;       // uint2 per layer
    const uint2* pp = (const uint2*)parts;
    const uint2 q0 = pp[i];
    const uint2 q1 = pp[i + LS];
    const uint2 q2 = pp[i + 2 * LS];
    const uint2 q3 = pp[i + 3 * LS];
    const float4 bb = ((const float4*)(scof + 1024))[i & 31];
    float4 s;
    s.x = ((bf2f((ushort)(q0.x & 0xffff)) + bf2f((ushort)(q1.x & 0xffff))) +
           (bf2f((ushort)(q2.x & 0xffff)) + bf2f((ushort)(q3.x & 0xffff)))) + bb.x;
    s.y = ((bf2f((ushort)(q0.x >> 16)) + bf2f((ushort)(q1.x >> 16))) +
           (bf2f((ushort)(q2.x >> 16)) + bf2f((ushort)(q3.x >> 16)))) + bb.y;
    s.z = ((bf2f((ushort)(q0.y & 0xffff)) + bf2f((ushort)(q1.y & 0xffff))) +
           (bf2f((ushort)(q2.y & 0xffff)) + bf2f((ushort)(q3.y & 0xffff)))) + bb.z;
    s.w = ((bf2f((ushort)(q0.y >> 16)) + bf2f((ushort)(q1.y >> 16))) +
           (bf2f((ushort)(q2.y >> 16)) + bf2f((ushort)(q3.y >> 16)))) + bb.w;
    ((float4*)out)[i] = s;
}

// ---------------- CSR build: deterministic two-pass multisplit -------------
__global__ __launch_bounds__(256) void bincount_k(const int* __restrict__ ei,
                                                  int* __restrict__ cnts) {
    __shared__ int hc[NBKT];
    const int chunk = blockIdx.x;
    const int hop = chunk >> 6, c = chunk & 63;
    for (int i = threadIdx.x; i < NBKT; i += 256) hc[i] = 0;
    __syncthreads();
    const int* dstp = ei + (size_t)hop * 2 * N_EDGES + N_EDGES + c * CHE;
    for (int i = threadIdx.x; i < CHE; i += 256)
        atomicAdd(&hc[dstp[i] >> 6], 1);
    __syncthreads();
    for (int b = threadIdx.x; b < NBKT; b += 256)
        cnts[((hop * NBKT + b) << 6) | c] = hc[b];
}

__global__ __launch_bounds__(1024) void scanA_k(int* __restrict__ cnts,
                                                int* __restrict__ bsums) {
    __shared__ int sh[1024];
    const int tid = threadIdx.x;
    const int i = blockIdx.x * 1024 + tid;
    const int v = cnts[i];
    sh[tid] = v;
    __syncthreads();
    int val = v;
    for (int off = 1; off < 1024; off <<= 1) {
        const int t = (tid >= off) ? sh[tid - off] : 0;
        __syncthreads();
        val += t;
        sh[tid] = val;
        __syncthreads();
    }
    cnts[i] = val - v;
    if (tid == 1023) bsums[blockIdx.x] = val;
}

// scanC with fused block-sum scan (each block redundantly scans 96 sums in LDS)
__global__ __launch_bounds__(1024) void scanC_k(int* __restrict__ cnts,
                                                const int* __restrict__ bsums,
                                                int* __restrict__ offs) {
    __shared__ int bs[128];
    const int tid = threadIdx.x;
    if (tid < 128) bs[tid] = (tid < SCAN_NBLK) ? bsums[tid] : 0;
    __syncthreads();
    for (int off = 1; off < 128; off <<= 1) {
        int t = 0;
        if (tid < 128 && tid >= off) t = bs[tid - off];
        __syncthreads();
        if (tid < 128) bs[tid] += t;
        __syncthreads();
    }
    const int add = (blockIdx.x == 0) ? 0 : bs[blockIdx.x - 1];
    const int i = blockIdx.x * 1024 + tid;
    cnts[i] += add;
    if (i == 0) offs[M_TOT] = E_TOT;
}

__global__ __launch_bounds__(256) void binplace_k(const int* __restrict__ ei,
                                                  const int* __restrict__ cnts,
                                                  uint* __restrict__ binned) {
    __shared__ int cur[NBKT];
    const int chunk = blockIdx.x;
    const int hop = chunk >> 6, c = chunk & 63;
    for (int b = threadIdx.x; b < NBKT; b += 256)
        cur[b] = cnts[((hop * NBKT + b) << 6) | c];
    __syncthreads();
    const int* srcp = ei + (size_t)hop * 2 * N_EDGES + c * CHE;
    const int* dstp = srcp + N_EDGES;
    for (int i = threadIdx.x; i < CHE; i += 256) {
        const int s = srcp[i], d = dstp[i];
        const int slot = atomicAdd(&cur[d >> 6], 1);
        binned[slot] = ((uint)(d & 63) << 16) | (uint)s;
    }
}

__global__ __launch_bounds__(256) void cat_k(const uint* __restrict__ binned,
                                             const int* __restrict__ cnts,
                                             int* __restrict__ offs,
                                             ushort* __restrict__ srcs) {
    const int B = blockIdx.x;
    const int hop = B >> 9, bb = B & 511;
    const int dstbase = bb << 6;
    if (dstbase >= N_NODES) return;
    const int bB = cnts[B << 6];
    const int bE = (B == NBKT_TOT - 1) ? E_TOT : cnts[(B + 1) << 6];
    const int cnt = bE - bB;

    __shared__ uint ent[2048];
    __shared__ ushort stg[2048];
    __shared__ int hist[64], cur[64];

    for (int d = threadIdx.x; d < 64; d += 256) hist[d] = 0;
    __syncthreads();
    for (int i = threadIdx.x; i < cnt; i += 256) {
        const uint e = binned[bB + i];
        ent[i] = e;
        atomicAdd(&hist[e >> 16], 1);
    }
    __syncthreads();
    if (threadIdx.x < 64) {
        const int v = hist[threadIdx.x];
        int x = v;
        for (int off = 1; off < 64; off <<= 1) {
            const int t = __shfl_up(x, off, 64);
            if (threadIdx.x >= off) x += t;
        }
        cur[threadIdx.x] = x - v;
        const int gd = dstbase + threadIdx.x;
        if (gd < N_NODES) offs[hop * N_NODES + gd] = bB + x - v;
    }
    __syncthreads();
    for (int i = threadIdx.x; i < cnt; i += 256) {
        const uint e = ent[i];
        const int lp = atomicAdd(&cur[e >> 16], 1);
        stg[lp] = (ushort)(e & 0xffffu);
    }
    __syncthreads();
    for (int i = threadIdx.x; i < cnt; i += 256)
        srcs[bB + i] = stg[i];
}

// ---------------- GIN aggregation, all 3 hops in one launch ----------------
// (round-6 version: 4 edge-streams of 16 lanes x uint4, 32 edges in flight)
__global__ __launch_bounds__(256) void agg_k(const ushort* __restrict__ xball,
                                             const int* __restrict__ offs,
                                             const ushort* __restrict__ srcs,
                                             const float* __restrict__ eps,
                                             ushort* __restrict__ zb) {
    const int gnode = blockIdx.x * 4 + (threadIdx.x >> 6);   // 0..89999
    const int hop = gnode / N_NODES;
    const int node = gnode - hop * N_NODES;
    const int lane = threadIdx.x & 63;
    const int eh = lane >> 4;            // edge stream 0..3
    const int cl = lane & 15;            // 16B chunk within the 256B row
    const float a = 1.0f + eps[hop];
    const uint4* x4 = (const uint4*)(xball + (size_t)(hop + 1) * N_NODES * D);

    float acc[8];
#pragma unroll
    for (int q = 0; q < 8; ++q) acc[q] = 0.f;
    if (eh == 0) {                       // self term on stream 0
        const uint4 sv = x4[(size_t)node * 16 + cl];
        const uint w[4] = {sv.x, sv.y, sv.z, sv.w};
#pragma unroll
        for (int q = 0; q < 4; ++q) {
            acc[2 * q]     = a * bf2f((ushort)(w[q] & 0xffff));
            acc[2 * q + 1] = a * bf2f((ushort)(w[q] >> 16));
        }
    }

    const int beg = offs[gnode], end = offs[gnode + 1];
    for (int i = beg; i < end; i += 32) {
        uint4 v[8];
#pragma unroll
        for (int u = 0; u < 8; ++u) {
            const int p = i + u * 4 + eh;
            v[u] = make_uint4(0u, 0u, 0u, 0u);
            if (p < end) v[u] = x4[(size_t)srcs[p] * 16 + cl];
        }
#pragma unroll
        for (int u = 0; u < 8; ++u) {
            const uint w[4] = {v[u].x, v[u].y, v[u].z, v[u].w};
#pragma unroll
            for (int q = 0; q < 4; ++q) {
                acc[2 * q]     += bf2f((ushort)(w[q] & 0xffff));
                acc[2 * q + 1] += bf2f((ushort)(w[q] >> 16));
            }
        }
    }
#pragma unroll
    for (int q = 0; q < 8; ++q) {
        acc[q] += __shfl_xor(acc[q], 16);
        acc[q] += __shfl_xor(acc[q], 32);
    }
    if (eh == 0) {
        uint4 o;
        o.x = (uint)f2bf(acc[0]) | ((uint)f2bf(acc[1]) << 16);
        o.y = (uint)f2bf(acc[2]) | ((uint)f2bf(acc[3]) << 16);
        o.z = (uint)f2bf(acc[4]) | ((uint)f2bf(acc[5]) << 16);
        o.w = (uint)f2bf(acc[6]) | ((uint)f2bf(acc[7]) << 16);
        ((uint4*)zb)[(size_t)gnode * 16 + cl] = o;
    }
}

// ---------------- driver ----------------
extern "C" void kernel_launch(void* const* d_in, const int* in_sizes, int n_in,
                              void* d_out, int out_size, void* d_ws, size_t ws_size,
                              hipStream_t stream)
{
    const float* xs  = (const float*)d_in[0];
    const int*   ei  = (const int*)d_in[1];
    const float* lW1 = (const float*)d_in[2];
    const float* lb1 = (const float*)d_in[3];
    const float* lg  = (const float*)d_in[4];
    const float* lbt = (const float*)d_in[5];
    const float* lm  = (const float*)d_in[6];
    const float* lv  = (const float*)d_in[7];
    const float* lW2 = (const float*)d_in[8];
    const float* lb2 = (const float*)d_in[9];
    const float* eps = (const float*)d_in[10];
    const float* cW1 = (const float*)d_in[11];
    const float* cb1 = (const float*)d_in[12];
    const float* cg  = (const float*)d_in[13];
    const float* cbt = (const float*)d_in[14];
    const float* cm  = (const float*)d_in[15];
    const float* cv  = (const float*)d_in[16];
    const float* cW2 = (const float*)d_in[17];
    const float* cb2 = (const float*)d_in[18];
    float* out = (float*)d_out;

    char* ws = (char*)d_ws;
    ushort* xball = (ushort*)ws; ws += (size_t)4 * N_NODES * D * sizeof(ushort);
    ushort* zb    = (ushort*)ws; ws += (size_t)H * N_NODES * D * sizeof(ushort);
    ushort* parts = (ushort*)ws; ws += (size_t)4 * N_NODES * D * sizeof(ushort);
    ushort* Wt    = (ushort*)ws; ws += (size_t)8 * D * D * sizeof(ushort);
    float*  scof  = (float*)ws;  ws += (size_t)(4 * 256 + 128) * sizeof(float);
    int* cnts     = (int*)ws;    ws += (size_t)CELLS * sizeof(int);
    int* bsums    = (int*)ws;    ws += 128 * sizeof(int);
    int* offs     = (int*)ws;    ws += (size_t)(M_TOT + 64) * sizeof(int);
    uint* binned  = (uint*)ws;   ws += (size_t)E_TOT * sizeof(uint);
    ushort* srcs  = (ushort*)ws;

    // merged prep: weights^T (blocks 0-7), BN coeffs (8), bf16 conv (9+)
    prep_k<<<9 + CONV_BLK, 256, 0, stream>>>(xs, lW1, lW2, cW1, cW2,
                                             lb1, lg, lbt, lm, lv,
                                             cb1, cg, cbt, cm, cv,
                                             lb2, cb2, Wt, scof, xball);

    // CSR via multisplit (scanB fused into scanC)
    bincount_k<<<H * NCH, 256, 0, stream>>>(ei, cnts);
    scanA_k<<<SCAN_NBLK, 1024, 0, stream>>>(cnts, bsums);
    scanC_k<<<SCAN_NBLK, 1024, 0, stream>>>(cnts, bsums, offs);
    binplace_k<<<H * NCH, 256, 0, stream>>>(ei, cnts, binned);
    cat_k<<<NBKT_TOT, 256, 0, stream>>>(binned, cnts, offs, srcs);

    // aggregation for all 3 hops, then layer-parallel MLP + reduce
    agg_k<<<M_TOT / 4, 256, 0, stream>>>(xball, offs, srcs, eps, zb);
    layerpar_k<<<TILES * 4, 256, 0, stream>>>(xs, zb, Wt, scof, parts);
    reduce_k<<<(N_NODES * D / 4) / 256, 256, 0, stream>>>(parts, scof, out);
}

// Round 11
// 155.571 us; speedup vs baseline: 1.2054x; 1.1364x over previous
//
#include <hip/hip_runtime.h>

#define N_NODES 30000
#define N_EDGES 480000
#define D 128
#define H 3
#define BN_EPS 1e-5f
#define M_TOT (H * N_NODES)
#define E_TOT (H * N_EDGES)

#define NCH 64                       // chunks per hop
#define CHE (N_EDGES / NCH)          // 7500 edges per chunk
#define NBKT 512                     // dst buckets per hop (dst>>6)
#define NBKT_TOT (H * NBKT)          // 1536
#define CELLS (NBKT_TOT * NCH)       // 98304 = 96 * 1024
#define SCAN_NBLK (CELLS / 1024)     // 96
#define CONV_N4 (3 * N_NODES * D / 4)        // slices 1..3 only
#define CONV_BLK ((CONV_N4 + 255) / 256)     // 11250
#define TILES ((N_NODES + 63) / 64)          // 469
#define PREP_FIX (H * NCH + 9)               // 192 bincount + 8 weights + 1 scof

typedef __attribute__((ext_vector_type(8))) short short8v;   // 8 x bf16
typedef __attribute__((ext_vector_type(4))) float f32x4;     // MFMA accumulator

__device__ __forceinline__ ushort f2bf(float f) {            // RNE f32 -> bf16
    uint u = __float_as_uint(f);
    u += 0x7fffu + ((u >> 16) & 1u);
    return (ushort)(u >> 16);
}
__device__ __forceinline__ float bf2f(ushort b) {
    return __uint_as_float(((uint)b) << 16);
}

// acc += bf16_pair(w) . bf16_pair(msk)   (one VOP3P instruction)
#define DOT2(accv, w, msk) \
    asm("v_dot2_f32_bf16 %0, %1, %2, %0" : "+v"(accv) : "v"(w), "v"(msk))

// ---------------- merged prep: bincount + weights^T + BN coeffs + bf16 conv
__global__ __launch_bounds__(256) void prep_k(
    const float* __restrict__ xs, const int* __restrict__ ei,
    const float* __restrict__ lW1, const float* __restrict__ lW2,
    const float* __restrict__ cW1, const float* __restrict__ cW2,
    const float* __restrict__ lb1, const float* __restrict__ lg,
    const float* __restrict__ lbt, const float* __restrict__ lm,
    const float* __restrict__ lv,
    const float* __restrict__ cb1, const float* __restrict__ cg,
    const float* __restrict__ cbt, const float* __restrict__ cm,
    const float* __restrict__ cv,
    const float* __restrict__ lb2, const float* __restrict__ cb2,
    ushort* __restrict__ Wt, float* __restrict__ scof,
    ushort* __restrict__ xball, int* __restrict__ cnts)
{
    const int bid = blockIdx.x;
    const int tid = threadIdx.x;
    if (bid < H * NCH) {                     // CSR pass 1: per-chunk histogram
        __shared__ int hc[NBKT];
        const int hop = bid >> 6, c = bid & 63;
        for (int i = tid; i < NBKT; i += 256) hc[i] = 0;
        __syncthreads();
        const int* dstp = ei + (size_t)hop * 2 * N_EDGES + N_EDGES + c * CHE;
        for (int i = tid; i < CHE; i += 256)
            atomicAdd(&hc[dstp[i] >> 6], 1);
        __syncthreads();
        for (int b = tid; b < NBKT; b += 256)
            cnts[((hop * NBKT + b) << 6) | c] = hc[b];
    } else if (bid < H * NCH + 8) {          // transpose+convert weight matrix
        const int mat = bid - H * NCH;
        const float* src;
        if (mat == 0) src = lW1;
        else if (mat == 1) src = lW2;
        else {
            const int k = (mat - 2) >> 1;
            src = ((mat & 1) == 0 ? cW1 : cW2) + (size_t)k * D * D;
        }
        ushort* dst = Wt + (size_t)mat * D * D;
        for (int idx = tid; idx < D * D; idx += 256) {
            const int n = idx >> 7, k = idx & 127;
            dst[idx] = f2bf(src[k * D + n]);
        }
    } else if (bid == H * NCH + 8) {         // BN scale/offset + total bias
        for (int t = tid; t < 512; t += 256) {
            const int L = t >> 7, c = t & 127;
            float g, v, b, m, bt;
            if (L == 0) { g = lg[c]; v = lv[c]; b = lb1[c]; m = lm[c]; bt = lbt[c]; }
            else {
                const int k = L - 1;
                g = cg[k * D + c]; v = cv[k * D + c]; b = cb1[k * D + c];
                m = cm[k * D + c]; bt = cbt[k * D + c];
            }
            const float s = g * rsqrtf(v + BN_EPS);
            scof[L * 256 + c] = s;
            scof[L * 256 + 128 + c] = (b - m) * s + bt;
        }
        if (tid < 128) {                     // btot = lb2 + sum_k cb2[k]
            float t = lb2[tid];
            for (int k = 0; k < H; ++k) t += cb2[k * D + tid];
            scof[1024 + tid] = t;
        }
    } else {                                 // f32 -> bf16 for xs slices 1..3
        const int i = (bid - PREP_FIX) * 256 + tid;
        if (i < CONV_N4) {
            const float4 v = ((const float4*)(xs + (size_t)N_NODES * D))[i];
            ushort4 o;
            o.x = f2bf(v.x); o.y = f2bf(v.y); o.z = f2bf(v.z); o.w = f2bf(v.w);
            ((ushort4*)(xball + (size_t)N_NODES * D))[i] = o;
        }
    }
}

// ---------------- Layer-parallel MLP: block = (tile, layer) ----------------
#define LW 136

__global__ __launch_bounds__(256) void layerpar_k(
    const float* __restrict__ xs0, const ushort* __restrict__ zb,
    const ushort* __restrict__ Wt, const float* __restrict__ scof,
    ushort* __restrict__ parts)
{
    __shared__ ushort Xs[64 * LW];    // 17.4 KB (A tile, then h tile)
    __shared__ ushort Ws[128 * LW];   // 34.8 KB (W1, then W2)
    const int L = blockIdx.x & 3, tile = blockIdx.x >> 2;
    const int row0 = tile * 64;
    const int tid = threadIdx.x;
    const int wave = tid >> 6, lane = tid & 63;
    const int m16 = lane & 15, kq = lane >> 4;

    const ushort* W1t = Wt + (size_t)(2 * L) * D * D;
    const ushort* W2t = W1t + D * D;
    const float* scL = scof + L * 256;

    if (L == 0) {
        for (int f = tid; f < 2048; f += 256) {
            const int r = f >> 5, c4 = (f & 31) << 2;
            const int gr = row0 + r;
            ushort4 v = make_ushort4(0, 0, 0, 0);
            if (gr < N_NODES) {
                const float4 fv = *(const float4*)(xs0 + (size_t)gr * D + c4);
                v.x = f2bf(fv.x); v.y = f2bf(fv.y);
                v.z = f2bf(fv.z); v.w = f2bf(fv.w);
            }
            *(ushort4*)(&Xs[r * LW + c4]) = v;
        }
    } else {
        const ushort* X = zb + (size_t)(L - 1) * N_NODES * D;
        for (int f = tid; f < 2048; f += 256) {
            const int r = f >> 5, c4 = (f & 31) << 2;
            const int gr = row0 + r;
            ushort4 v = make_ushort4(0, 0, 0, 0);
            if (gr < N_NODES) v = *(const ushort4*)(X + (size_t)gr * D + c4);
            *(ushort4*)(&Xs[r * LW + c4]) = v;
        }
    }
    for (int f = tid; f < 4096; f += 256) {
        const int n = f >> 5, c4 = (f & 31) << 2;
        *(ushort4*)(&Ws[n * LW + c4]) = *(const ushort4*)(W1t + n * D + c4);
    }
    __syncthreads();

    const int arow = wave * 16 + m16;
    short8v a[4];
#pragma unroll
    for (int kk = 0; kk < 4; ++kk)
        a[kk] = *(const short8v*)(&Xs[arow * LW + kk * 32 + kq * 8]);

    f32x4 acc[8];
#pragma unroll
    for (int t = 0; t < 8; ++t) acc[t] = (f32x4){0.f, 0.f, 0.f, 0.f};
#pragma unroll
    for (int kk = 0; kk < 4; ++kk) {
#pragma unroll
        for (int t = 0; t < 8; ++t) {
            const short8v b = *(const short8v*)(&Ws[(t * 16 + m16) * LW + kk * 32 + kq * 8]);
            acc[t] = __builtin_amdgcn_mfma_f32_16x16x32_bf16(a[kk], b, acc[t], 0, 0, 0);
        }
    }
    __syncthreads();

#pragma unroll
    for (int t = 0; t < 8; ++t) {
        const int n = t * 16 + m16;
        const float sc = scL[n], of = scL[128 + n];
#pragma unroll
        for (int r = 0; r < 4; ++r)
            Xs[(wave * 16 + kq * 4 + r) * LW + n] = f2bf(fmaxf(acc[t][r] * sc + of, 0.f));
    }
    for (int f = tid; f < 4096; f += 256) {
        const int n = f >> 5, c4 = (f & 31) << 2;
        *(ushort4*)(&Ws[n * LW + c4]) = *(const ushort4*)(W2t + n * D + c4);
    }
    __syncthreads();

    short8v ah[4];
#pragma unroll
    for (int kk = 0; kk < 4; ++kk)
        ah[kk] = *(const short8v*)(&Xs[arow * LW + kk * 32 + kq * 8]);
    f32x4 accO[8];
#pragma unroll
    for (int t = 0; t < 8; ++t) accO[t] = (f32x4){0.f, 0.f, 0.f, 0.f};
#pragma unroll
    for (int kk = 0; kk < 4; ++kk) {
#pragma unroll
        for (int t = 0; t < 8; ++t) {
            const short8v b = *(const short8v*)(&Ws[(t * 16 + m16) * LW + kk * 32 + kq * 8]);
            accO[t] = __builtin_amdgcn_mfma_f32_16x16x32_bf16(ah[kk], b, accO[t], 0, 0, 0);
        }
    }

    ushort* pL = parts + (size_t)L * N_NODES * D;
#pragma unroll
    for (int t = 0; t < 8; ++t) {
        const int n = t * 16 + m16;
#pragma unroll
        for (int r = 0; r < 4; ++r) {
            const int gr = row0 + wave * 16 + kq * 4 + r;
            if (gr < N_NODES) pL[(size_t)gr * D + n] = f2bf(accO[t][r]);
        }
    }
}

// ---------------- reduce: out = sum_L parts[L] + btot (f32, fixed order) ---
__global__ __launch_bounds__(256) void reduce_k(const ushort* __restrict__ parts,
                                                const float* __restrict__ scof,
                                                float* __restrict__ out)
{
    const int i = blockIdx.x * 256 + threadIdx.x;    // uint2 granule = 4 cols
    const size_t LS = (size_t)N_NODES * D / 4;       // uint2 per layer
    const uint2* pp = (const uint2*)parts;
    const uint2 q0 = pp[i];
    const uint2 q1 = pp[i + LS];
    const uint2 q2 = pp[i + 2 * LS];
    const uint2 q3 = pp[i + 3 * LS];
    const float4 bb = ((const float4*)(scof + 1024))[i & 31];
    float4 s;
    s.x = ((bf2f((ushort)(q0.x & 0xffff)) + bf2f((ushort)(q1.x & 0xffff))) +
           (bf2f((ushort)(q2.x & 0xffff)) + bf2f((ushort)(q3.x & 0xffff)))) + bb.x;
    s.y = ((bf2f((ushort)(q0.x >> 16)) + bf2f((ushort)(q1.x >> 16))) +
           (bf2f((ushort)(q2.x >> 16)) + bf2f((ushort)(q3.x >> 16)))) + bb.y;
    s.z = ((bf2f((ushort)(q0.y & 0xffff)) + bf2f((ushort)(q1.y & 0xffff))) +
           (bf2f((ushort)(q2.y & 0xffff)) + bf2f((ushort)(q3.y & 0xffff)))) + bb.z;
    s.w = ((bf2f((ushort)(q0.y >> 16)) + bf2f((ushort)(q1.y >> 16))) +
           (bf2f((ushort)(q2.y >> 16)) + bf2f((ushort)(q3.y >> 16)))) + bb.w;
    ((float4*)out)[i] = s;
}

// ---------------- CSR scans ----------------
__global__ __launch_bounds__(1024) void scanA_k(int* __restrict__ cnts,
                                                int* __restrict__ bsums) {
    __shared__ int sh[1024];
    const int tid = threadIdx.x;
    const int i = blockIdx.x * 1024 + tid;
    const int v = cnts[i];
    sh[tid] = v;
    __syncthreads();
    int val = v;
    for (int off = 1; off < 1024; off <<= 1) {
        const int t = (tid >= off) ? sh[tid - off] : 0;
        __syncthreads();
        val += t;
        sh[tid] = val;
        __syncthreads();
    }
    cnts[i] = val - v;
    if (tid == 1023) bsums[blockIdx.x] = val;
}

__global__ __launch_bounds__(1024) void scanC_k(int* __restrict__ cnts,
                                                const int* __restrict__ bsums,
                                                int* __restrict__ offs) {
    __shared__ int bs[128];
    const int tid = threadIdx.x;
    if (tid < 128) bs[tid] = (tid < SCAN_NBLK) ? bsums[tid] : 0;
    __syncthreads();
    for (int off = 1; off < 128; off <<= 1) {
        int t = 0;
        if (tid < 128 && tid >= off) t = bs[tid - off];
        __syncthreads();
        if (tid < 128) bs[tid] += t;
        __syncthreads();
    }
    const int add = (blockIdx.x == 0) ? 0 : bs[blockIdx.x - 1];
    const int i = blockIdx.x * 1024 + tid;
    cnts[i] += add;
    if (i == 0) offs[M_TOT] = E_TOT;
}

__global__ __launch_bounds__(256) void binplace_k(const int* __restrict__ ei,
                                                  const int* __restrict__ cnts,
                                                  uint* __restrict__ binned) {
    __shared__ int cur[NBKT];
    const int chunk = blockIdx.x;
    const int hop = chunk >> 6, c = chunk & 63;
    for (int b = threadIdx.x; b < NBKT; b += 256)
        cur[b] = cnts[((hop * NBKT + b) << 6) | c];
    __syncthreads();
    const int* srcp = ei + (size_t)hop * 2 * N_EDGES + c * CHE;
    const int* dstp = srcp + N_EDGES;
    for (int i = threadIdx.x; i < CHE; i += 256) {
        const int s = srcp[i], d = dstp[i];
        const int slot = atomicAdd(&cur[d >> 6], 1);
        binned[slot] = ((uint)(d & 63) << 16) | (uint)s;
    }
}

__global__ __launch_bounds__(256) void cat_k(const uint* __restrict__ binned,
                                             const int* __restrict__ cnts,
                                             int* __restrict__ offs,
                                             ushort* __restrict__ srcs) {
    const int B = blockIdx.x;
    const int hop = B >> 9, bb = B & 511;
    const int dstbase = bb << 6;
    if (dstbase >= N_NODES) return;
    const int bB = cnts[B << 6];
    const int bE = (B == NBKT_TOT - 1) ? E_TOT : cnts[(B + 1) << 6];
    const int cnt = bE - bB;

    __shared__ uint ent[2048];
    __shared__ ushort stg[2048];
    __shared__ int hist[64], cur[64];

    for (int d = threadIdx.x; d < 64; d += 256) hist[d] = 0;
    __syncthreads();
    for (int i = threadIdx.x; i < cnt; i += 256) {
        const uint e = binned[bB + i];
        ent[i] = e;
        atomicAdd(&hist[e >> 16], 1);
    }
    __syncthreads();
    if (threadIdx.x < 64) {
        const int v = hist[threadIdx.x];
        int x = v;
        for (int off = 1; off < 64; off <<= 1) {
            const int t = __shfl_up(x, off, 64);
            if (threadIdx.x >= off) x += t;
        }
        cur[threadIdx.x] = x - v;
        const int gd = dstbase + threadIdx.x;
        if (gd < N_NODES) offs[hop * N_NODES + gd] = bB + x - v;
    }
    __syncthreads();
    for (int i = threadIdx.x; i < cnt; i += 256) {
        const uint e = ent[i];
        const int lp = atomicAdd(&cur[e >> 16], 1);
        stg[lp] = (ushort)(e & 0xffffu);
    }
    __syncthreads();
    for (int i = threadIdx.x; i < cnt; i += 256)
        srcs[bB + i] = stg[i];
}

// ---------------- GIN aggregation: dot2 accumulate + 32-bit offsets --------
// one wave per (hop,node); 4 edge-streams of 16 lanes x uint4 (32 edges in
// flight). v_dot2_f32_bf16 with (1,0)/(0,1) masks: 2 insts per packed pair
// (vs 4 for shift/and+add). 32-bit voffset -> saddr-form global loads.
__global__ __launch_bounds__(256) void agg_k(const ushort* __restrict__ xball,
                                             const int* __restrict__ offs,
                                             const ushort* __restrict__ srcs,
                                             const float* __restrict__ eps,
                                             ushort* __restrict__ zb) {
    const int gnode = blockIdx.x * 4 + (threadIdx.x >> 6);   // 0..89999
    const int hop = gnode / N_NODES;
    const int node = gnode - hop * N_NODES;
    const int lane = threadIdx.x & 63;
    const int eh = lane >> 4;            // edge stream 0..3
    const int cl = lane & 15;            // 16B chunk within the 256B row
    const float a = 1.0f + eps[hop];
    const char* xb = (const char*)(xball + (size_t)(hop + 1) * N_NODES * D);
    const uint coff = (uint)cl << 4;
    const uint MLO = 0x00003F80u;        // bf16 (1.0, 0)
    const uint MHI = 0x3F800000u;        // bf16 (0, 1.0)

    float acc[8];
#pragma unroll
    for (int q = 0; q < 8; ++q) acc[q] = 0.f;
    if (eh == 0) {                       // self term on stream 0
        const uint4 sv = *(const uint4*)(xb + (((uint)node << 8) + coff));
        const uint w[4] = {sv.x, sv.y, sv.z, sv.w};
#pragma unroll
        for (int q = 0; q < 4; ++q) {
            acc[2 * q]     = a * bf2f((ushort)(w[q] & 0xffff));
            acc[2 * q + 1] = a * bf2f((ushort)(w[q] >> 16));
        }
    }

    const int beg = offs[gnode], end = offs[gnode + 1];
    for (int i = beg; i < end; i += 32) {
        uint4 v[8];
#pragma unroll
        for (int u = 0; u < 8; ++u) {
            const int p = i + u * 4 + eh;
            v[u] = make_uint4(0u, 0u, 0u, 0u);
            if (p < end) {
                const uint boff = ((uint)srcs[p] << 8) + coff;
                v[u] = *(const uint4*)(xb + boff);
            }
        }
#pragma unroll
        for (int u = 0; u < 8; ++u) {
            DOT2(acc[0], v[u].x, MLO); DOT2(acc[1], v[u].x, MHI);
            DOT2(acc[2], v[u].y, MLO); DOT2(acc[3], v[u].y, MHI);
            DOT2(acc[4], v[u].z, MLO); DOT2(acc[5], v[u].z, MHI);
            DOT2(acc[6], v[u].w, MLO); DOT2(acc[7], v[u].w, MHI);
        }
    }
#pragma unroll
    for (int q = 0; q < 8; ++q) {
        acc[q] += __shfl_xor(acc[q], 16);
        acc[q] += __shfl_xor(acc[q], 32);
    }
    if (eh == 0) {
        uint4 o;
        o.x = (uint)f2bf(acc[0]) | ((uint)f2bf(acc[1]) << 16);
        o.y = (uint)f2bf(acc[2]) | ((uint)f2bf(acc[3]) << 16);
        o.z = (uint)f2bf(acc[4]) | ((uint)f2bf(acc[5]) << 16);
        o.w = (uint)f2bf(acc[6]) | ((uint)f2bf(acc[7]) << 16);
        ((uint4*)zb)[(size_t)gnode * 16 + cl] = o;
    }
}

// ---------------- driver ----------------
extern "C" void kernel_launch(void* const* d_in, const int* in_sizes, int n_in,
                              void* d_out, int out_size, void* d_ws, size_t ws_size,
                              hipStream_t stream)
{
    const float* xs  = (const float*)d_in[0];
    const int*   ei  = (const int*)d_in[1];
    const float* lW1 = (const float*)d_in[2];
    const float* lb1 = (const float*)d_in[3];
    const float* lg  = (const float*)d_in[4];
    const float* lbt = (const float*)d_in[5];
    const float* lm  = (const float*)d_in[6];
    const float* lv  = (const float*)d_in[7];
    const float* lW2 = (const float*)d_in[8];
    const float* lb2 = (const float*)d_in[9];
    const float* eps = (const float*)d_in[10];
    const float* cW1 = (const float*)d_in[11];
    const float* cb1 = (const float*)d_in[12];
    const float* cg  = (const float*)d_in[13];
    const float* cbt = (const float*)d_in[14];
    const float* cm  = (const float*)d_in[15];
    const float* cv  = (const float*)d_in[16];
    const float* cW2 = (const float*)d_in[17];
    const float* cb2 = (const float*)d_in[18];
    float* out = (float*)d_out;

    char* ws = (char*)d_ws;
    ushort* xball = (ushort*)ws; ws += (size_t)4 * N_NODES * D * sizeof(ushort);
    ushort* zb    = (ushort*)ws; ws += (size_t)H * N_NODES * D * sizeof(ushort);
    ushort* parts = (ushort*)ws; ws += (size_t)4 * N_NODES * D * sizeof(ushort);
    ushort* Wt    = (ushort*)ws; ws += (size_t)8 * D * D * sizeof(ushort);
    float*  scof  = (float*)ws;  ws += (size_t)(4 * 256 + 128) * sizeof(float);
    int* cnts     = (int*)ws;    ws += (size_t)CELLS * sizeof(int);
    int* bsums    = (int*)ws;    ws += 128 * sizeof(int);
    int* offs     = (int*)ws;    ws += (size_t)(M_TOT + 64) * sizeof(int);
    uint* binned  = (uint*)ws;   ws += (size_t)E_TOT * sizeof(uint);
    ushort* srcs  = (ushort*)ws;

    // merged prep: bincount (0..191), weights^T (192..199), BN (200), conv
    prep_k<<<PREP_FIX + CONV_BLK, 256, 0, stream>>>(
        xs, ei, lW1, lW2, cW1, cW2, lb1, lg, lbt, lm, lv,
        cb1, cg, cbt, cm, cv, lb2, cb2, Wt, scof, xball, cnts);

    // CSR scans + placement
    scanA_k<<<SCAN_NBLK, 1024, 0, stream>>>(cnts, bsums);
    scanC_k<<<SCAN_NBLK, 1024, 0, stream>>>(cnts, bsums, offs);
    binplace_k<<<H * NCH, 256, 0, stream>>>(ei, cnts, binned);
    cat_k<<<NBKT_TOT, 256, 0, stream>>>(binned, cnts, offs, srcs);

    // aggregation for all 3 hops, then layer-parallel MLP + reduce
    agg_k<<<M_TOT / 4, 256, 0, stream>>>(xball, offs, srcs, eps, zb);
    layerpar_k<<<TILES * 4, 256, 0, stream>>>(xs, zb, Wt, scof, parts);
    reduce_k<<<(N_NODES * D / 4) / 256, 256, 0, stream>>>(parts, scof, out);
}